// Round 1
// baseline (1369.298 us; speedup 1.0000x reference)
//
#include <hip/hip_runtime.h>
#include <hip/hip_bf16.h>
#include <stdint.h>

typedef __bf16 bf16;
typedef bf16 bf16x8 __attribute__((ext_vector_type(8)));
typedef float f32x4 __attribute__((ext_vector_type(4)));

#define MFMA_BF16(a, b, c) __builtin_amdgcn_mfma_f32_16x16x32_bf16((a), (b), (c), 0, 0, 0)

// problem constants
#define BB 8
#define LL 4160
#define DD 1024
#define HH 16
#define NTT 4096
#define NTOK (BB * LL)   // 33280
#define NSPLIT 13
#define KCHUNK 320       // 13*320 = 4160

__device__ __forceinline__ f32x4 zero4() {
  f32x4 z = {0.0f, 0.0f, 0.0f, 0.0f};
  return z;
}

typedef __attribute__((address_space(1))) void as1_void;
typedef __attribute__((address_space(3))) void as3_void;

// async global->LDS, 16B per lane; LDS dest is wave-uniform base + lane*16
__device__ __forceinline__ void glds16(const void* g, void* l) {
  __builtin_amdgcn_global_load_lds((as1_void*)(uintptr_t)g, (as3_void*)l, 16, 0,
                                   0);
}

__device__ __forceinline__ float loadS(const void* p, size_t idx, int f32) {
  return f32 ? ((const float*)p)[idx] : (float)((const bf16*)p)[idx];
}

// load 8 fp32 (two aligned f32x4) and convert to bf16x8
__device__ __forceinline__ bf16x8 cvt8(const float* p) {
  const f32x4 a = *(const f32x4*)p;
  const f32x4 b = *(const f32x4*)(p + 4);
  bf16x8 r;
#pragma unroll
  for (int j = 0; j < 4; ++j) {
    r[j] = (bf16)a[j];
    r[j + 4] = (bf16)b[j];
  }
  return r;
}

// Flexible-dtype store of 8 contiguous elements from a bf16 source buffer.
__device__ __forceinline__ void storeOut8(void* out, size_t idx,
                                          const bf16* src, int f32) {
  if (f32) {
    float* o = (float*)out + idx;
#pragma unroll
    for (int j = 0; j < 8; ++j) o[j] = (float)src[j];
  } else {
    *(bf16x8*)((bf16*)out + idx) = *(const bf16x8*)src;
  }
}

// ---------------------------------------------------------------------------
// Dtype probe: bf16 N(0,1) data has biased-exponent in ~[116,130] and never
// hits 0x00/0xFF; fp32 data's low uint16s are ~uniform -> ~256/65536 hits.
// ---------------------------------------------------------------------------
__global__ __launch_bounds__(256) void detect_dtype(
    const unsigned short* __restrict__ q, int* __restrict__ flag) {
  __shared__ int cnt;
  if (threadIdx.x == 0) cnt = 0;
  __syncthreads();
  int c = 0;
  for (int i = threadIdx.x; i < 65536; i += 256) {
    const int e = (q[i] >> 7) & 0xFF;
    c += (e == 0 || e == 0xFF) ? 1 : 0;
  }
  atomicAdd(&cnt, c);
  __syncthreads();
  if (threadIdx.x == 0) *flag = (cnt > 64) ? 1 : 0;
}

// ---------------------------------------------------------------------------
// flex (fp32|bf16) -> bf16 elementwise convert/copy, 8 elems/thread
// ---------------------------------------------------------------------------
__global__ __launch_bounds__(256) void to_bf16(const void* __restrict__ in,
                                               bf16* __restrict__ out, int n8,
                                               const int* __restrict__ dflag) {
  const int f = *dflag;
  const int t = blockIdx.x * 256 + threadIdx.x;
  if (t >= n8) return;
  const size_t idx = (size_t)t * 8;
  if (f) {
    *(bf16x8*)(out + idx) = cvt8((const float*)in + idx);
  } else {
    *(bf16x8*)(out + idx) = *(const bf16x8*)((const bf16*)in + idx);
  }
}

// ---------------------------------------------------------------------------
// C[M,N] = A[M,K] @ W[N,K]^T + bias[N]   (A flex, W bf16 ws, bf16 out)
// 128x128 tile, BK=32, 4 waves each computing 64x64 via 4x4 MFMA 16x16x32.
// m97 structure: global_load_lds dwordx4 staging (bf16 path); fp32-A path
// reg-stages via vectorized f32x4 loads + convert. XCD-swizzled block ids.
// ---------------------------------------------------------------------------
__global__ __launch_bounds__(256) void gemm_bt(
    const void* __restrict__ A, const bf16* __restrict__ W,
    const void* __restrict__ bias, int b_off, bf16* __restrict__ C, int M,
    int N, int K, int ntn, const int* __restrict__ dflag, int a_ext) {
  __shared__ __align__(16) bf16 As[128 * 32];
  __shared__ __align__(16) bf16 Bs[128 * 32];
  const int f = *dflag;
  const int af32 = a_ext ? f : 0;
  const int tid = threadIdx.x;
  const int wave = tid >> 6;
  const int lane = tid & 63;
  const int quad = lane >> 4;
  const int m16 = lane & 15;
  // XCD-aware swizzle (gridDim.x % 8 == 0): 8 col-tiles of one A row-panel
  // land on one XCD's L2.
  const int bid = (blockIdx.x & 7) * (gridDim.x >> 3) + (blockIdx.x >> 3);
  const int row0 = (bid / ntn) * 128;
  const int col0 = (bid % ntn) * 128;
  const int wm = (wave >> 1) * 64;
  const int wn = (wave & 1) * 64;

  f32x4 acc[4][4];
#pragma unroll
  for (int i = 0; i < 4; ++i)
#pragma unroll
    for (int j = 0; j < 4; ++j) acc[i][j] = zero4();

  // global_load_lds staging: wave w covers tile rows [w*32, w*32+32) in two
  // 1KB issues; lane l sources row w*32+p*16+(l>>2), col (l&3)*8.
  const int srow = wave * 32 + (lane >> 2);
  const int scol = (lane & 3) * 8;
  const bf16* Ab = (const bf16*)A;
  const size_t gA0 = (size_t)(row0 + srow) * K + scol;
  const size_t gA1 = gA0 + (size_t)16 * K;
  const size_t gW0 = (size_t)(col0 + srow) * K + scol;
  const size_t gW1 = gW0 + (size_t)16 * K;
  bf16* lA0 = &As[wave * 1024];
  bf16* lA1 = &As[wave * 1024 + 512];
  bf16* lB0 = &Bs[wave * 1024];
  bf16* lB1 = &Bs[wave * 1024 + 512];

  // fp32-A reg staging: thread t covers rows sr, sr+64, cols sc..sc+7
  const int sr = tid >> 2;
  const int sc = (tid & 3) * 8;
  const float* Af = (const float*)A;
  const size_t fA0 = (size_t)(row0 + sr) * K + sc;
  const size_t fA1 = (size_t)(row0 + sr + 64) * K + sc;

  for (int kb = 0; kb < K; kb += 32) {
    bf16x8 a0, a1;
    if (af32) {
      a0 = cvt8(Af + fA0 + kb);
      a1 = cvt8(Af + fA1 + kb);
    }
    __syncthreads();  // previous iteration's LDS readers done
    if (af32) {
      *(bf16x8*)&As[sr * 32 + sc] = a0;
      *(bf16x8*)&As[(sr + 64) * 32 + sc] = a1;
    } else {
      glds16(Ab + gA0 + kb, lA0);
      glds16(Ab + gA1 + kb, lA1);
    }
    glds16(W + gW0 + kb, lB0);
    glds16(W + gW1 + kb, lB1);
    __syncthreads();  // drains vmcnt(0): LDS tiles complete
    bf16x8 af_[4], bf_[4];
#pragma unroll
    for (int i = 0; i < 4; ++i)
      af_[i] = *(const bf16x8*)&As[(wm + i * 16 + m16) * 32 + quad * 8];
#pragma unroll
    for (int j = 0; j < 4; ++j)
      bf_[j] = *(const bf16x8*)&Bs[(wn + j * 16 + m16) * 32 + quad * 8];
#pragma unroll
    for (int i = 0; i < 4; ++i)
#pragma unroll
      for (int j = 0; j < 4; ++j)
        acc[i][j] = MFMA_BF16(af_[i], bf_[j], acc[i][j]);
  }

#pragma unroll
  for (int j = 0; j < 4; ++j) {
    const int col = col0 + wn + j * 16 + m16;
    const float bv = loadS(bias, b_off + col, f);
#pragma unroll
    for (int i = 0; i < 4; ++i) {
      const int row = row0 + wm + i * 16 + quad * 4;
#pragma unroll
      for (int r = 0; r < 4; ++r)
        C[(size_t)(row + r) * N + col] = (bf16)(acc[i][j][r] + bv);
    }
  }
}

// ---------------------------------------------------------------------------
// Temporal block attention: one block per (b, nb, h), 4 waves, one 16-row
// q-tile per wave sharing Qs/Ks/Vt. 64 q x 128 k x 64 dh.
// ---------------------------------------------------------------------------
__global__ __launch_bounds__(256) void temporal_attn(
    const bf16* __restrict__ Q, const bf16* __restrict__ K,
    const bf16* __restrict__ V, const void* __restrict__ tmask,
    const void* __restrict__ smask, void* __restrict__ Out,
    const int* __restrict__ dflag) {
  __shared__ __align__(16) char smem[42496];
  bf16* Qs = (bf16*)smem;                 // [64][64]   8KB
  bf16* Ks = (bf16*)(smem + 8192);        // [128][64] 16KB
  bf16* Vt = (bf16*)(smem + 24576);       // [64][136] (dh-major, padded)
  float* biasS = (float*)(smem + 41984);  // [128]
  bf16* P = (bf16*)smem;                  // [64][136] aliases Qs+Ks
  bf16* Ost = (bf16*)smem;                // [64][64] aliases P after PV

  const int f = *dflag;
  const int bid = blockIdx.x;
  const int h = bid & 15;
  const int nb = (bid >> 4) & 63;
  const int b = bid >> 10;
  const int tid = threadIdx.x;
  const int wq = tid >> 6;  // wave = q-tile index 0..3
  const int lane = tid & 63;
  const int quad = lane >> 4;
  const int m16 = lane & 15;

  const size_t tbase = ((size_t)b * LL + nb * 64) * DD + h * 64;
  const size_t sbase = ((size_t)b * LL + NTT) * DD + h * 64;

  // cooperative staging across all 256 threads
  {
    const int r = tid >> 3;         // 0..31
    const int cc = (tid & 7) * 8;
    *(bf16x8*)&Qs[r * 64 + cc] = *(const bf16x8*)&Q[tbase + (size_t)r * DD + cc];
    *(bf16x8*)&Qs[(r + 32) * 64 + cc] =
        *(const bf16x8*)&Q[tbase + (size_t)(r + 32) * DD + cc];
    *(bf16x8*)&Ks[r * 64 + cc] = *(const bf16x8*)&K[tbase + (size_t)r * DD + cc];
    *(bf16x8*)&Ks[(r + 32) * 64 + cc] =
        *(const bf16x8*)&K[tbase + (size_t)(r + 32) * DD + cc];
    *(bf16x8*)&Ks[(64 + r) * 64 + cc] =
        *(const bf16x8*)&K[sbase + (size_t)r * DD + cc];
    *(bf16x8*)&Ks[(96 + r) * 64 + cc] =
        *(const bf16x8*)&K[sbase + (size_t)(r + 32) * DD + cc];
  }
  // V transposed into Vt[dh][k] (lane = dh column); wave wq does k-chunks
#pragma unroll
  for (int t = 0; t < 4; ++t) {
    const int kb = wq * 4 + t;
    bf16x8 tmp;
#pragma unroll
    for (int j = 0; j < 8; ++j) {
      const int kk = kb * 8 + j;
      const size_t rowb = (kk < 64) ? (tbase + (size_t)kk * DD)
                                    : (sbase + (size_t)(kk - 64) * DD);
      tmp[j] = V[rowb + lane];
    }
    *(bf16x8*)&Vt[lane * 136 + kb * 8] = tmp;
  }
  if (tid < 128) {
    const float mv = (tid < 64)
                         ? loadS(tmask, ((size_t)b * 64 + nb) * 64 + tid, f)
                         : loadS(smask, b * 64 + (tid - 64), f);
    biasS[tid] = (mv > 0.5f) ? 0.0f : -1e30f;
  }
  __syncthreads();

  // S = Q @ K^T  (this wave's q-tile x 8 k-tiles)
  f32x4 s[8];
#pragma unroll
  for (int kt = 0; kt < 8; ++kt) s[kt] = zero4();
#pragma unroll
  for (int ks = 0; ks < 2; ++ks) {
    const bf16x8 aq =
        *(const bf16x8*)&Qs[(wq * 16 + m16) * 64 + ks * 32 + quad * 8];
#pragma unroll
    for (int kt = 0; kt < 8; ++kt) {
      const bf16x8 bk =
          *(const bf16x8*)&Ks[(kt * 16 + m16) * 64 + ks * 32 + quad * 8];
      s[kt] = MFMA_BF16(aq, bk, s[kt]);
    }
  }

  const float scale = 0.125f;
  float invl[4];
#pragma unroll
  for (int r = 0; r < 4; ++r) {
    float mx = -1e30f;
#pragma unroll
    for (int kt = 0; kt < 8; ++kt) {
      float v = s[kt][r] * scale + biasS[kt * 16 + m16];
      s[kt][r] = v;
      mx = fmaxf(mx, v);
    }
#pragma unroll
    for (int off = 1; off < 16; off <<= 1) mx = fmaxf(mx, __shfl_xor(mx, off));
    float sum = 0.0f;
#pragma unroll
    for (int kt = 0; kt < 8; ++kt) {
      float p = __expf(s[kt][r] - mx);
      s[kt][r] = p;
      sum += p;
    }
#pragma unroll
    for (int off = 1; off < 16; off <<= 1) sum += __shfl_xor(sum, off);
    invl[r] = 1.0f / sum;
  }
  __syncthreads();  // all waves done reading Qs/Ks (P aliases them)
  // P (normalized) -> LDS, wave-local rows only
#pragma unroll
  for (int kt = 0; kt < 8; ++kt)
#pragma unroll
    for (int r = 0; r < 4; ++r)
      P[(wq * 16 + quad * 4 + r) * 136 + kt * 16 + m16] =
          (bf16)(s[kt][r] * invl[r]);

  // O = P @ V  (wave reads only its own P rows; Vt is stable)
  f32x4 o[4];
#pragma unroll
  for (int j = 0; j < 4; ++j) o[j] = zero4();
#pragma unroll
  for (int ks = 0; ks < 4; ++ks) {
    const bf16x8 ap =
        *(const bf16x8*)&P[(wq * 16 + m16) * 136 + ks * 32 + quad * 8];
#pragma unroll
    for (int j = 0; j < 4; ++j) {
      const bf16x8 bv =
          *(const bf16x8*)&Vt[(j * 16 + m16) * 136 + ks * 32 + quad * 8];
      o[j] = MFMA_BF16(ap, bv, o[j]);
    }
  }
  __syncthreads();  // all waves done with P (Ost aliases it)
#pragma unroll
  for (int j = 0; j < 4; ++j)
#pragma unroll
    for (int r = 0; r < 4; ++r)
      Ost[(wq * 16 + quad * 4 + r) * 64 + j * 16 + m16] = (bf16)o[j][r];
  __syncthreads();
  {
    const int r = tid >> 3;
    const int cc = (tid & 7) * 8;
    storeOut8(Out, tbase + (size_t)r * DD + cc, &Ost[r * 64 + cc], f);
    storeOut8(Out, tbase + (size_t)(r + 32) * DD + cc, &Ost[(r + 32) * 64 + cc],
              f);
  }
}

// ---------------------------------------------------------------------------
// Static attention, flash split-K: one wave per (b, h, split of 320 keys).
// ---------------------------------------------------------------------------
__global__ __launch_bounds__(64) void static_attn(
    const bf16* __restrict__ Q2, const bf16* __restrict__ K2,
    const bf16* __restrict__ V2, const void* __restrict__ tmask,
    const void* __restrict__ smask, float* __restrict__ Opart,
    float* __restrict__ Mpart, float* __restrict__ Lpart,
    const int* __restrict__ dflag) {
  __shared__ __align__(16) char smem[34816];
  bf16* Qs = (bf16*)smem;            // [64][64]
  bf16* Ks = (bf16*)(smem + 8192);   // [64][64]
  bf16* Vt = (bf16*)(smem + 16384);  // [64][72]
  bf16* P = (bf16*)(smem + 25600);   // [64][72]

  const int f = *dflag;
  const int bid = blockIdx.x;
  const int sp = bid % NSPLIT;
  const int bh = bid / NSPLIT;
  const int h = bh & 15;
  const int b = bh >> 4;
  const int lane = threadIdx.x;
  const int quad = lane >> 4;
  const int m16 = lane & 15;

  {
    const int r = lane >> 3, cc = (lane & 7) * 8;
#pragma unroll
    for (int j = 0; j < 8; ++j) {
      const int rr = j * 8 + r;
      *(bf16x8*)&Qs[rr * 64 + cc] =
          *(const bf16x8*)&Q2[((size_t)(b * 64 + rr)) * DD + h * 64 + cc];
    }
  }

  const float scale = 0.125f;
  float m_run[4][4], l_run[4][4];
  f32x4 o[4][4];
#pragma unroll
  for (int i = 0; i < 4; ++i)
#pragma unroll
    for (int r = 0; r < 4; ++r) {
      m_run[i][r] = -1e30f;
      l_run[i][r] = 0.0f;
    }
#pragma unroll
  for (int i = 0; i < 4; ++i)
#pragma unroll
    for (int j = 0; j < 4; ++j) o[i][j] = zero4();

  const int k0 = sp * KCHUNK;
  for (int t = 0; t < 5; ++t) {
    const int kt0 = k0 + t * 64;
    __syncthreads();
    {
      const int r = lane >> 3, cc = (lane & 7) * 8;
#pragma unroll
      for (int j = 0; j < 8; ++j) {
        const int rr = j * 8 + r;
        *(bf16x8*)&Ks[rr * 64 + cc] =
            *(const bf16x8*)&K2[((size_t)b * LL + kt0 + rr) * DD + h * 64 + cc];
      }
    }
#pragma unroll
    for (int kb = 0; kb < 8; ++kb) {
      bf16x8 tmp;
#pragma unroll
      for (int j = 0; j < 8; ++j)
        tmp[j] = V2[((size_t)b * LL + kt0 + kb * 8 + j) * DD + h * 64 + lane];
      *(bf16x8*)&Vt[lane * 72 + kb * 8] = tmp;
    }
    __syncthreads();

    f32x4 s[4][4];
#pragma unroll
    for (int i = 0; i < 4; ++i)
#pragma unroll
      for (int nt = 0; nt < 4; ++nt) s[i][nt] = zero4();
#pragma unroll
    for (int ks = 0; ks < 2; ++ks) {
      bf16x8 aq[4];
#pragma unroll
      for (int i = 0; i < 4; ++i)
        aq[i] = *(const bf16x8*)&Qs[(i * 16 + m16) * 64 + ks * 32 + quad * 8];
#pragma unroll
      for (int nt = 0; nt < 4; ++nt) {
        const bf16x8 bk =
            *(const bf16x8*)&Ks[(nt * 16 + m16) * 64 + ks * 32 + quad * 8];
#pragma unroll
        for (int i = 0; i < 4; ++i) s[i][nt] = MFMA_BF16(aq[i], bk, s[i][nt]);
      }
    }
    float bias_nt[4];
#pragma unroll
    for (int nt = 0; nt < 4; ++nt) {
      const int kg = kt0 + nt * 16 + m16;
      float mv;
      if (kg < NTT)
        mv = loadS(tmask, (size_t)b * NTT + kg, f);
      else
        mv = loadS(smask, b * 64 + (kg - NTT), f);
      bias_nt[nt] = (mv > 0.5f) ? 0.0f : -1e30f;
    }
#pragma unroll
    for (int i = 0; i < 4; ++i)
#pragma unroll
      for (int r = 0; r < 4; ++r) {
        float mx = -1e30f;
#pragma unroll
        for (int nt = 0; nt < 4; ++nt) {
          float v = s[i][nt][r] * scale + bias_nt[nt];
          s[i][nt][r] = v;
          mx = fmaxf(mx, v);
        }
#pragma unroll
        for (int off = 1; off < 16; off <<= 1)
          mx = fmaxf(mx, __shfl_xor(mx, off));
        const float m_new = fmaxf(m_run[i][r], mx);
        const float alpha = __expf(m_run[i][r] - m_new);
        float sum = 0.0f;
#pragma unroll
        for (int nt = 0; nt < 4; ++nt) {
          float p = __expf(s[i][nt][r] - m_new);
          s[i][nt][r] = p;
          sum += p;
        }
#pragma unroll
        for (int off = 1; off < 16; off <<= 1) sum += __shfl_xor(sum, off);
        l_run[i][r] = l_run[i][r] * alpha + sum;
        m_run[i][r] = m_new;
#pragma unroll
        for (int j = 0; j < 4; ++j) o[i][j][r] *= alpha;
      }
#pragma unroll
    for (int i = 0; i < 4; ++i)
#pragma unroll
      for (int nt = 0; nt < 4; ++nt)
#pragma unroll
        for (int r = 0; r < 4; ++r)
          P[(i * 16 + quad * 4 + r) * 72 + nt * 16 + m16] = (bf16)s[i][nt][r];
    __syncthreads();
#pragma unroll
    for (int ks = 0; ks < 2; ++ks) {
      bf16x8 ap[4], bv[4];
#pragma unroll
      for (int i = 0; i < 4; ++i)
        ap[i] = *(const bf16x8*)&P[(i * 16 + m16) * 72 + ks * 32 + quad * 8];
#pragma unroll
      for (int j = 0; j < 4; ++j)
        bv[j] = *(const bf16x8*)&Vt[(j * 16 + m16) * 72 + ks * 32 + quad * 8];
#pragma unroll
      for (int i = 0; i < 4; ++i)
#pragma unroll
        for (int j = 0; j < 4; ++j) o[i][j] = MFMA_BF16(ap[i], bv[j], o[i][j]);
    }
  }

  const size_t obase = ((size_t)bh * NSPLIT + sp) * 4096;
#pragma unroll
  for (int i = 0; i < 4; ++i)
#pragma unroll
    for (int j = 0; j < 4; ++j)
#pragma unroll
      for (int r = 0; r < 4; ++r)
        Opart[obase + (size_t)(i * 16 + quad * 4 + r) * 64 + j * 16 + m16] =
            o[i][j][r];
  if (m16 == 0) {
    const size_t mbase = ((size_t)bh * NSPLIT + sp) * 64;
#pragma unroll
    for (int i = 0; i < 4; ++i)
#pragma unroll
      for (int r = 0; r < 4; ++r) {
        Mpart[mbase + i * 16 + quad * 4 + r] = m_run[i][r];
        Lpart[mbase + i * 16 + quad * 4 + r] = l_run[i][r];
      }
  }
}

__global__ __launch_bounds__(64) void static_merge(
    const float* __restrict__ Opart, const float* __restrict__ Mpart,
    const float* __restrict__ Lpart, bf16* __restrict__ Sout) {
  const int bh = blockIdx.x;
  const int b = bh >> 4, h = bh & 15;
  const int lane = threadIdx.x;
  for (int r = 0; r < 64; ++r) {
    float M = -1e30f;
    float ms[NSPLIT];
#pragma unroll
    for (int s = 0; s < NSPLIT; ++s) {
      ms[s] = Mpart[((size_t)bh * NSPLIT + s) * 64 + r];
      M = fmaxf(M, ms[s]);
    }
    float L = 0.0f;
    float acc = 0.0f;
#pragma unroll
    for (int s = 0; s < NSPLIT; ++s) {
      const float w = __expf(ms[s] - M);
      L += Lpart[((size_t)bh * NSPLIT + s) * 64 + r] * w;
      acc += w * Opart[(((size_t)bh * NSPLIT + s) * 64 + r) * 64 + lane];
    }
    Sout[((size_t)(b * 64 + r)) * DD + h * 64 + lane] = (bf16)(acc / L);
  }
}

__global__ __launch_bounds__(256) void gather_qs(const bf16* __restrict__ Q,
                                                 bf16* __restrict__ Q2in) {
  const int t = blockIdx.x * 256 + threadIdx.x;  // 65536 total
  const int row = t >> 7;
  const int cc = (t & 127) * 8;
  const int b = row >> 6, i = row & 63;
  *(bf16x8*)&Q2in[(size_t)row * DD + cc] =
      *(const bf16x8*)&Q[((size_t)b * LL + NTT + i) * DD + cc];
}

__global__ __launch_bounds__(256) void scatter_out(const bf16* __restrict__ S,
                                                   void* __restrict__ Out,
                                                   const int* __restrict__ dflag) {
  const int f = *dflag;
  const int t = blockIdx.x * 256 + threadIdx.x;
  const int row = t >> 7;
  const int cc = (t & 127) * 8;
  const int b = row >> 6, i = row & 63;
  storeOut8(Out, ((size_t)b * LL + NTT + i) * DD + cc, &S[(size_t)row * DD + cc],
            f);
}

extern "C" void kernel_launch(void* const* d_in, const int* in_sizes, int n_in,
                              void* d_out, int out_size, void* d_ws,
                              size_t ws_size, hipStream_t stream) {
  // Size-driven input identification (dtype-independent: sizes are element
  // counts). q,k,v = the 34078720s in order; Wq,Wk,Wv,out_w = the 1048576s;
  // bq,bk,bv,out_b = the 1024s; masks 32768/512; in_proj 3145728/3072.
  const void* qkv[3] = {nullptr, nullptr, nullptr};
  const void* W4[4] = {nullptr, nullptr, nullptr, nullptr};
  const void* b4[4] = {nullptr, nullptr, nullptr, nullptr};
  const void *tmask = nullptr, *smask = nullptr, *ipw = nullptr, *ipb = nullptr;
  int nbig = 0, nw = 0, nb_ = 0;
  for (int i = 0; i < n_in; ++i) {
    switch (in_sizes[i]) {
      case 34078720: if (nbig < 3) qkv[nbig++] = d_in[i]; break;
      case 32768: tmask = d_in[i]; break;
      case 512: smask = d_in[i]; break;
      case 1048576: if (nw < 4) W4[nw++] = d_in[i]; break;
      case 1024: if (nb_ < 4) b4[nb_++] = d_in[i]; break;
      case 3145728: ipw = d_in[i]; break;
      case 3072: ipb = d_in[i]; break;
      default: break;
    }
  }

  char* w = (char*)d_ws;
  int* dflag = (int*)w; w += 256;
  const size_t BIG = (size_t)NTOK * DD * 2;  // 68,157,440 B
  bf16* Qb = (bf16*)w;  w += BIG;
  bf16* Kb = (bf16*)w;  w += BIG;
  bf16* Vb = (bf16*)w;  w += BIG;
  bf16* Q2in = (bf16*)w;  w += (size_t)512 * DD * 2;
  bf16* Q2 = (bf16*)w;    w += (size_t)512 * DD * 2;
  bf16* SoutB = (bf16*)w; w += (size_t)512 * DD * 2;
  bf16* SoutF = (bf16*)w; w += (size_t)512 * DD * 2;
  float* Opart = (float*)w; w += (size_t)128 * NSPLIT * 4096 * 4;
  float* Mpart = (float*)w; w += (size_t)128 * NSPLIT * 64 * 4;
  float* Lpart = (float*)w; w += (size_t)128 * NSPLIT * 64 * 4;
  bf16* wW3 = (bf16*)w; w += (size_t)1048576 * 2;  // out_w (live at step 11)
  // Weights dead before static_attn writes Opart (stream-serial): overlay
  // Wq/Wk/Wv/in_proj bf16 copies inside the Opart region (12.6MB <= 27.3MB).
  bf16* wW0 = (bf16*)Opart;
  bf16* wW1 = wW0 + 1048576;
  bf16* wW2 = wW1 + 1048576;
  bf16* wIp = wW2 + 1048576;

  // 0: decide external dtype on-device (deterministic; graph-safe)
  detect_dtype<<<1, 256, 0, stream>>>((const unsigned short*)qkv[0], dflag);
  // 0.x: weights -> bf16 ws (copy if already bf16)
  to_bf16<<<512, 256, 0, stream>>>(W4[0], wW0, 131072, dflag);
  to_bf16<<<512, 256, 0, stream>>>(W4[1], wW1, 131072, dflag);
  to_bf16<<<512, 256, 0, stream>>>(W4[2], wW2, 131072, dflag);
  to_bf16<<<512, 256, 0, stream>>>(W4[3], wW3, 131072, dflag);
  to_bf16<<<1536, 256, 0, stream>>>(ipw, wIp, 393216, dflag);
  // 1-3: QKV projections (A external -> flex)
  gemm_bt<<<2080, 256, 0, stream>>>(qkv[0], wW0, b4[0], 0, Qb, NTOK, DD, DD, 8,
                                    dflag, 1);
  gemm_bt<<<2080, 256, 0, stream>>>(qkv[1], wW1, b4[1], 0, Kb, NTOK, DD, DD, 8,
                                    dflag, 1);
  gemm_bt<<<2080, 256, 0, stream>>>(qkv[2], wW2, b4[2], 0, Vb, NTOK, DD, DD, 8,
                                    dflag, 1);
  // 4: gather static Q rows before Qb is reused
  gather_qs<<<256, 256, 0, stream>>>(Qb, Q2in);
  // 5: temporal attention -> Out rows [b*4160, b*4160+4096)
  temporal_attn<<<BB * 64 * HH, 256, 0, stream>>>(Qb, Kb, Vb, tmask, smask,
                                                  d_out, dflag);
  // 6-7: second projections (k2 into Qb, v2 into Kb)
  gemm_bt<<<2080, 256, 0, stream>>>(Kb, wIp + (size_t)DD * DD, ipb, DD, Qb,
                                    NTOK, DD, DD, 8, dflag, 0);
  gemm_bt<<<2080, 256, 0, stream>>>(Vb, wIp + (size_t)2 * DD * DD, ipb, 2 * DD,
                                    Kb, NTOK, DD, DD, 8, dflag, 0);
  // 8: q2 projection (M=512)
  gemm_bt<<<32, 256, 0, stream>>>(Q2in, wIp, ipb, 0, Q2, 512, DD, DD, 8, dflag,
                                  0);
  // 9-10: static attention (split-K flash) + merge
  static_attn<<<128 * NSPLIT, 64, 0, stream>>>(Q2, Qb, Kb, tmask, smask, Opart,
                                               Mpart, Lpart, dflag);
  static_merge<<<128, 64, 0, stream>>>(Opart, Mpart, Lpart, SoutB);
  // 11-12: output projection + scatter into Out static rows
  gemm_bt<<<32, 256, 0, stream>>>(SoutB, wW3, b4[3], 0, SoutF, 512, DD, DD, 8,
                                  dflag, 0);
  scatter_out<<<256, 256, 0, stream>>>(SoutF, d_out, dflag);
}

// Round 4
// 1256.878 us; speedup vs baseline: 1.0894x; 1.0894x over previous
//
#include <hip/hip_runtime.h>
#include <hip/hip_bf16.h>
#include <stdint.h>

typedef __bf16 bf16;
typedef bf16 bf16x8 __attribute__((ext_vector_type(8)));
typedef float f32x4 __attribute__((ext_vector_type(4)));

#define MFMA_BF16(a, b, c) __builtin_amdgcn_mfma_f32_16x16x32_bf16((a), (b), (c), 0, 0, 0)

// problem constants
#define BB 8
#define LL 4160
#define DD 1024
#define HH 16
#define NTT 4096
#define NTOK (BB * LL)   // 33280
#define NSPLIT 13
#define KCHUNK 320       // 13*320 = 4160

__device__ __forceinline__ f32x4 zero4() {
  f32x4 z = {0.0f, 0.0f, 0.0f, 0.0f};
  return z;
}

typedef __attribute__((address_space(1))) void as1_void;
typedef __attribute__((address_space(3))) void as3_void;

// async global->LDS, 16B per lane; LDS dest is wave-uniform base + lane*16
__device__ __forceinline__ void glds16(const void* g, void* l) {
  __builtin_amdgcn_global_load_lds((as1_void*)(uintptr_t)g, (as3_void*)l, 16, 0,
                                   0);
}

__device__ __forceinline__ float loadS(const void* p, size_t idx, int f32) {
  return f32 ? ((const float*)p)[idx] : (float)((const bf16*)p)[idx];
}

// load 8 fp32 (two aligned f32x4) and convert to bf16x8
__device__ __forceinline__ bf16x8 cvt8(const float* p) {
  const f32x4 a = *(const f32x4*)p;
  const f32x4 b = *(const f32x4*)(p + 4);
  bf16x8 r;
#pragma unroll
  for (int j = 0; j < 4; ++j) {
    r[j] = (bf16)a[j];
    r[j + 4] = (bf16)b[j];
  }
  return r;
}

// Flexible-dtype store of 8 contiguous elements from a bf16 source buffer.
__device__ __forceinline__ void storeOut8(void* out, size_t idx,
                                          const bf16* src, int f32) {
  if (f32) {
    float* o = (float*)out + idx;
#pragma unroll
    for (int j = 0; j < 8; ++j) o[j] = (float)src[j];
  } else {
    *(bf16x8*)((bf16*)out + idx) = *(const bf16x8*)src;
  }
}

// ---------------------------------------------------------------------------
// Dtype probe: bf16 N(0,1) data has biased-exponent in ~[116,130] and never
// hits 0x00/0xFF; fp32 data's low uint16s are ~uniform -> ~256/65536 hits.
// ---------------------------------------------------------------------------
__global__ __launch_bounds__(256) void detect_dtype(
    const unsigned short* __restrict__ q, int* __restrict__ flag) {
  __shared__ int cnt;
  if (threadIdx.x == 0) cnt = 0;
  __syncthreads();
  int c = 0;
  for (int i = threadIdx.x; i < 65536; i += 256) {
    const int e = (q[i] >> 7) & 0xFF;
    c += (e == 0 || e == 0xFF) ? 1 : 0;
  }
  atomicAdd(&cnt, c);
  __syncthreads();
  if (threadIdx.x == 0) *flag = (cnt > 64) ? 1 : 0;
}

// ---------------------------------------------------------------------------
// flex (fp32|bf16) -> bf16 elementwise convert/copy, 8 elems/thread.
// only_f32: skip entirely when input already bf16 (consumer reads ext ptr).
// ---------------------------------------------------------------------------
__global__ __launch_bounds__(256) void to_bf16(const void* __restrict__ in,
                                               bf16* __restrict__ out, int n8,
                                               const int* __restrict__ dflag,
                                               int only_f32) {
  const int f = *dflag;
  if (only_f32 && !f) return;
  const int t = blockIdx.x * 256 + threadIdx.x;
  if (t >= n8) return;
  const size_t idx = (size_t)t * 8;
  if (f) {
    *(bf16x8*)(out + idx) = cvt8((const float*)in + idx);
  } else {
    *(bf16x8*)(out + idx) = *(const bf16x8*)((const bf16*)in + idx);
  }
}

// ---------------------------------------------------------------------------
// C[M,N] = A[M,K] @ W[N,K]^T + bias[N]   (A bf16 (ext or staged), W bf16 ws,
// bf16 out, fp32 accum). 128x128 tile, BK=32, 4 waves each 64x64 via 4x4
// MFMA 16x16x32. Depth-3 software pipeline (T3+T4): global_load_lds into a
// 3-buffer LDS ring, counted s_waitcnt vmcnt(4) + raw s_barrier per K-step
// (never vmcnt(0) in steady state). sched_barrier(0) after each barrier pins
// the following ds_reads below it (rule-18 fence). XCD-swizzled bids (T1).
// ---------------------------------------------------------------------------
__global__ __launch_bounds__(256) void gemm_bt(
    const void* __restrict__ Aext, const bf16* __restrict__ Astg,
    const bf16* __restrict__ W, const void* __restrict__ bias, int b_off,
    bf16* __restrict__ C, int M, int N, int K, int ntn,
    const int* __restrict__ dflag, int a_ext) {
  __shared__ __align__(16) bf16 As[3][128 * 32];
  __shared__ __align__(16) bf16 Bs[3][128 * 32];
  const int f = *dflag;
  const bf16* A = (a_ext && f) ? Astg : (const bf16*)Aext;
  const int tid = threadIdx.x;
  const int wave = tid >> 6;
  const int lane = tid & 63;
  const int quad = lane >> 4;
  const int m16 = lane & 15;
  // XCD-aware swizzle (gridDim.x % 8 == 0)
  const int bid = (blockIdx.x & 7) * (gridDim.x >> 3) + (blockIdx.x >> 3);
  const int row0 = (bid / ntn) * 128;
  const int col0 = (bid % ntn) * 128;
  const int wm = (wave >> 1) * 64;
  const int wn = (wave & 1) * 64;

  f32x4 acc[4][4];
#pragma unroll
  for (int i = 0; i < 4; ++i)
#pragma unroll
    for (int j = 0; j < 4; ++j) acc[i][j] = zero4();

  // staging: wave w covers tile rows [w*32, w*32+32) in two 1KB issues;
  // lane l sources row w*32+p*16+(l>>2), col (l&3)*8 -> LDS elem base+lane*8.
  const int srow = wave * 32 + (lane >> 2);
  const int scol = (lane & 3) * 8;
  const size_t gA0 = (size_t)(row0 + srow) * K + scol;
  const size_t gA1 = gA0 + (size_t)16 * K;
  const size_t gW0 = (size_t)(col0 + srow) * K + scol;
  const size_t gW1 = gW0 + (size_t)16 * K;

  const int T = K >> 5;

#define STAGE_TILE(s, t)                                    \
  do {                                                      \
    const size_t kb_ = (size_t)(t) << 5;                    \
    glds16(A + gA0 + kb_, &As[(s)][wave * 1024]);           \
    glds16(A + gA1 + kb_, &As[(s)][wave * 1024 + 512]);     \
    glds16(W + gW0 + kb_, &Bs[(s)][wave * 1024]);           \
    glds16(W + gW1 + kb_, &Bs[(s)][wave * 1024 + 512]);     \
  } while (0)

  // prologue: tiles 0 and 1 in flight; retire tile 0 (4 newest stay aloft)
  STAGE_TILE(0, 0);
  STAGE_TILE(1, 1);
  asm volatile("s_waitcnt vmcnt(4)" ::: "memory");
  __builtin_amdgcn_s_barrier();
  __builtin_amdgcn_sched_barrier(0);

  int cur = 0;
  for (int t = 0; t < T; ++t) {
    const int pf = t + 2;
    if (pf < T) {
      const int s = (cur == 0) ? 2 : cur - 1;  // buffer freed at end of t-1
      STAGE_TILE(s, pf);
    }
    bf16x8 af_[4], bf_[4];
#pragma unroll
    for (int i = 0; i < 4; ++i)
      af_[i] = *(const bf16x8*)&As[cur][(wm + i * 16 + m16) * 32 + quad * 8];
#pragma unroll
    for (int j = 0; j < 4; ++j)
      bf_[j] = *(const bf16x8*)&Bs[cur][(wn + j * 16 + m16) * 32 + quad * 8];
#pragma unroll
    for (int i = 0; i < 4; ++i)
#pragma unroll
      for (int j = 0; j < 4; ++j)
        acc[i][j] = MFMA_BF16(af_[i], bf_[j], acc[i][j]);
    // steady state: {t+1:4, t+2:4} in flight -> vmcnt(4) retires t+1's.
    // tail (no prefetch issued): drain to 0 so t+1's loads are complete.
    if (pf < T)
      asm volatile("s_waitcnt vmcnt(4)" ::: "memory");
    else
      asm volatile("s_waitcnt vmcnt(0)" ::: "memory");
    __builtin_amdgcn_s_barrier();
    __builtin_amdgcn_sched_barrier(0);
    cur = (cur == 2) ? 0 : cur + 1;
  }
#undef STAGE_TILE

#pragma unroll
  for (int j = 0; j < 4; ++j) {
    const int col = col0 + wn + j * 16 + m16;
    const float bv = loadS(bias, b_off + col, f);
#pragma unroll
    for (int i = 0; i < 4; ++i) {
      const int row = row0 + wm + i * 16 + quad * 4;
#pragma unroll
      for (int r = 0; r < 4; ++r)
        C[(size_t)(row + r) * N + col] = (bf16)(acc[i][j][r] + bv);
    }
  }
}

// ---------------------------------------------------------------------------
// Temporal block attention: one block per (b, nb, h), 4 waves, one 16-row
// q-tile per wave sharing Qs/Ks/Vt. 64 q x 128 k x 64 dh.
// ---------------------------------------------------------------------------
__global__ __launch_bounds__(256) void temporal_attn(
    const bf16* __restrict__ Q, const bf16* __restrict__ K,
    const bf16* __restrict__ V, const void* __restrict__ tmask,
    const void* __restrict__ smask, void* __restrict__ Out,
    const int* __restrict__ dflag) {
  __shared__ __align__(16) char smem[42496];
  bf16* Qs = (bf16*)smem;                 // [64][64]   8KB
  bf16* Ks = (bf16*)(smem + 8192);        // [128][64] 16KB
  bf16* Vt = (bf16*)(smem + 24576);       // [64][136] (dh-major, padded)
  float* biasS = (float*)(smem + 41984);  // [128]
  bf16* P = (bf16*)smem;                  // [64][136] aliases Qs+Ks
  bf16* Ost = (bf16*)smem;                // [64][64] aliases P after PV

  const int f = *dflag;
  const int bid = blockIdx.x;
  const int h = bid & 15;
  const int nb = (bid >> 4) & 63;
  const int b = bid >> 10;
  const int tid = threadIdx.x;
  const int wq = tid >> 6;  // wave = q-tile index 0..3
  const int lane = tid & 63;
  const int quad = lane >> 4;
  const int m16 = lane & 15;

  const size_t tbase = ((size_t)b * LL + nb * 64) * DD + h * 64;
  const size_t sbase = ((size_t)b * LL + NTT) * DD + h * 64;

  // cooperative staging across all 256 threads
  {
    const int r = tid >> 3;         // 0..31
    const int cc = (tid & 7) * 8;
    *(bf16x8*)&Qs[r * 64 + cc] = *(const bf16x8*)&Q[tbase + (size_t)r * DD + cc];
    *(bf16x8*)&Qs[(r + 32) * 64 + cc] =
        *(const bf16x8*)&Q[tbase + (size_t)(r + 32) * DD + cc];
    *(bf16x8*)&Ks[r * 64 + cc] = *(const bf16x8*)&K[tbase + (size_t)r * DD + cc];
    *(bf16x8*)&Ks[(r + 32) * 64 + cc] =
        *(const bf16x8*)&K[tbase + (size_t)(r + 32) * DD + cc];
    *(bf16x8*)&Ks[(64 + r) * 64 + cc] =
        *(const bf16x8*)&K[sbase + (size_t)r * DD + cc];
    *(bf16x8*)&Ks[(96 + r) * 64 + cc] =
        *(const bf16x8*)&K[sbase + (size_t)(r + 32) * DD + cc];
  }
  // V transposed into Vt[dh][k] (lane = dh column); wave wq does k-chunks
#pragma unroll
  for (int t = 0; t < 4; ++t) {
    const int kb = wq * 4 + t;
    bf16x8 tmp;
#pragma unroll
    for (int j = 0; j < 8; ++j) {
      const int kk = kb * 8 + j;
      const size_t rowb = (kk < 64) ? (tbase + (size_t)kk * DD)
                                    : (sbase + (size_t)(kk - 64) * DD);
      tmp[j] = V[rowb + lane];
    }
    *(bf16x8*)&Vt[lane * 136 + kb * 8] = tmp;
  }
  if (tid < 128) {
    const float mv = (tid < 64)
                         ? loadS(tmask, ((size_t)b * 64 + nb) * 64 + tid, f)
                         : loadS(smask, b * 64 + (tid - 64), f);
    biasS[tid] = (mv > 0.5f) ? 0.0f : -1e30f;
  }
  __syncthreads();

  // S = Q @ K^T  (this wave's q-tile x 8 k-tiles)
  f32x4 s[8];
#pragma unroll
  for (int kt = 0; kt < 8; ++kt) s[kt] = zero4();
#pragma unroll
  for (int ks = 0; ks < 2; ++ks) {
    const bf16x8 aq =
        *(const bf16x8*)&Qs[(wq * 16 + m16) * 64 + ks * 32 + quad * 8];
#pragma unroll
    for (int kt = 0; kt < 8; ++kt) {
      const bf16x8 bk =
          *(const bf16x8*)&Ks[(kt * 16 + m16) * 64 + ks * 32 + quad * 8];
      s[kt] = MFMA_BF16(aq, bk, s[kt]);
    }
  }

  const float scale = 0.125f;
  float invl[4];
#pragma unroll
  for (int r = 0; r < 4; ++r) {
    float mx = -1e30f;
#pragma unroll
    for (int kt = 0; kt < 8; ++kt) {
      float v = s[kt][r] * scale + biasS[kt * 16 + m16];
      s[kt][r] = v;
      mx = fmaxf(mx, v);
    }
#pragma unroll
    for (int off = 1; off < 16; off <<= 1) mx = fmaxf(mx, __shfl_xor(mx, off));
    float sum = 0.0f;
#pragma unroll
    for (int kt = 0; kt < 8; ++kt) {
      float p = __expf(s[kt][r] - mx);
      s[kt][r] = p;
      sum += p;
    }
#pragma unroll
    for (int off = 1; off < 16; off <<= 1) sum += __shfl_xor(sum, off);
    invl[r] = 1.0f / sum;
  }
  __syncthreads();  // all waves done reading Qs/Ks (P aliases them)
  // P (normalized) -> LDS, wave-local rows only
#pragma unroll
  for (int kt = 0; kt < 8; ++kt)
#pragma unroll
    for (int r = 0; r < 4; ++r)
      P[(wq * 16 + quad * 4 + r) * 136 + kt * 16 + m16] =
          (bf16)(s[kt][r] * invl[r]);

  // O = P @ V  (wave reads only its own P rows; Vt is stable)
  f32x4 o[4];
#pragma unroll
  for (int j = 0; j < 4; ++j) o[j] = zero4();
#pragma unroll
  for (int ks = 0; ks < 4; ++ks) {
    const bf16x8 ap =
        *(const bf16x8*)&P[(wq * 16 + m16) * 136 + ks * 32 + quad * 8];
#pragma unroll
    for (int j = 0; j < 4; ++j) {
      const bf16x8 bv =
          *(const bf16x8*)&Vt[(j * 16 + m16) * 136 + ks * 32 + quad * 8];
      o[j] = MFMA_BF16(ap, bv, o[j]);
    }
  }
  __syncthreads();  // all waves done with P (Ost aliases it)
#pragma unroll
  for (int j = 0; j < 4; ++j)
#pragma unroll
    for (int r = 0; r < 4; ++r)
      Ost[(wq * 16 + quad * 4 + r) * 64 + j * 16 + m16] = (bf16)o[j][r];
  __syncthreads();
  {
    const int r = tid >> 3;
    const int cc = (tid & 7) * 8;
    storeOut8(Out, tbase + (size_t)r * DD + cc, &Ost[r * 64 + cc], f);
    storeOut8(Out, tbase + (size_t)(r + 32) * DD + cc, &Ost[(r + 32) * 64 + cc],
              f);
  }
}

// ---------------------------------------------------------------------------
// Static attention, flash split-K: one wave per (b, h, split of 320 keys).
// ---------------------------------------------------------------------------
__global__ __launch_bounds__(64) void static_attn(
    const bf16* __restrict__ Q2, const bf16* __restrict__ K2,
    const bf16* __restrict__ V2, const void* __restrict__ tmask,
    const void* __restrict__ smask, float* __restrict__ Opart,
    float* __restrict__ Mpart, float* __restrict__ Lpart,
    const int* __restrict__ dflag) {
  __shared__ __align__(16) char smem[34816];
  bf16* Qs = (bf16*)smem;            // [64][64]
  bf16* Ks = (bf16*)(smem + 8192);   // [64][64]
  bf16* Vt = (bf16*)(smem + 16384);  // [64][72]
  bf16* P = (bf16*)(smem + 25600);   // [64][72]

  const int f = *dflag;
  const int bid = blockIdx.x;
  const int sp = bid % NSPLIT;
  const int bh = bid / NSPLIT;
  const int h = bh & 15;
  const int b = bh >> 4;
  const int lane = threadIdx.x;
  const int quad = lane >> 4;
  const int m16 = lane & 15;

  {
    const int r = lane >> 3, cc = (lane & 7) * 8;
#pragma unroll
    for (int j = 0; j < 8; ++j) {
      const int rr = j * 8 + r;
      *(bf16x8*)&Qs[rr * 64 + cc] =
          *(const bf16x8*)&Q2[((size_t)(b * 64 + rr)) * DD + h * 64 + cc];
    }
  }

  const float scale = 0.125f;
  float m_run[4][4], l_run[4][4];
  f32x4 o[4][4];
#pragma unroll
  for (int i = 0; i < 4; ++i)
#pragma unroll
    for (int r = 0; r < 4; ++r) {
      m_run[i][r] = -1e30f;
      l_run[i][r] = 0.0f;
    }
#pragma unroll
  for (int i = 0; i < 4; ++i)
#pragma unroll
    for (int j = 0; j < 4; ++j) o[i][j] = zero4();

  const int k0 = sp * KCHUNK;
  for (int t = 0; t < 5; ++t) {
    const int kt0 = k0 + t * 64;
    __syncthreads();
    {
      const int r = lane >> 3, cc = (lane & 7) * 8;
#pragma unroll
      for (int j = 0; j < 8; ++j) {
        const int rr = j * 8 + r;
        *(bf16x8*)&Ks[rr * 64 + cc] =
            *(const bf16x8*)&K2[((size_t)b * LL + kt0 + rr) * DD + h * 64 + cc];
      }
    }
#pragma unroll
    for (int kb = 0; kb < 8; ++kb) {
      bf16x8 tmp;
#pragma unroll
      for (int j = 0; j < 8; ++j)
        tmp[j] = V2[((size_t)b * LL + kt0 + kb * 8 + j) * DD + h * 64 + lane];
      *(bf16x8*)&Vt[lane * 72 + kb * 8] = tmp;
    }
    __syncthreads();

    f32x4 s[4][4];
#pragma unroll
    for (int i = 0; i < 4; ++i)
#pragma unroll
      for (int nt = 0; nt < 4; ++nt) s[i][nt] = zero4();
#pragma unroll
    for (int ks = 0; ks < 2; ++ks) {
      bf16x8 aq[4];
#pragma unroll
      for (int i = 0; i < 4; ++i)
        aq[i] = *(const bf16x8*)&Qs[(i * 16 + m16) * 64 + ks * 32 + quad * 8];
#pragma unroll
      for (int nt = 0; nt < 4; ++nt) {
        const bf16x8 bk =
            *(const bf16x8*)&Ks[(nt * 16 + m16) * 64 + ks * 32 + quad * 8];
#pragma unroll
        for (int i = 0; i < 4; ++i) s[i][nt] = MFMA_BF16(aq[i], bk, s[i][nt]);
      }
    }
    float bias_nt[4];
#pragma unroll
    for (int nt = 0; nt < 4; ++nt) {
      const int kg = kt0 + nt * 16 + m16;
      float mv;
      if (kg < NTT)
        mv = loadS(tmask, (size_t)b * NTT + kg, f);
      else
        mv = loadS(smask, b * 64 + (kg - NTT), f);
      bias_nt[nt] = (mv > 0.5f) ? 0.0f : -1e30f;
    }
#pragma unroll
    for (int i = 0; i < 4; ++i)
#pragma unroll
      for (int r = 0; r < 4; ++r) {
        float mx = -1e30f;
#pragma unroll
        for (int nt = 0; nt < 4; ++nt) {
          float v = s[i][nt][r] * scale + bias_nt[nt];
          s[i][nt][r] = v;
          mx = fmaxf(mx, v);
        }
#pragma unroll
        for (int off = 1; off < 16; off <<= 1)
          mx = fmaxf(mx, __shfl_xor(mx, off));
        const float m_new = fmaxf(m_run[i][r], mx);
        const float alpha = __expf(m_run[i][r] - m_new);
        float sum = 0.0f;
#pragma unroll
        for (int nt = 0; nt < 4; ++nt) {
          float p = __expf(s[i][nt][r] - m_new);
          s[i][nt][r] = p;
          sum += p;
        }
#pragma unroll
        for (int off = 1; off < 16; off <<= 1) sum += __shfl_xor(sum, off);
        l_run[i][r] = l_run[i][r] * alpha + sum;
        m_run[i][r] = m_new;
#pragma unroll
        for (int j = 0; j < 4; ++j) o[i][j][r] *= alpha;
      }
#pragma unroll
    for (int i = 0; i < 4; ++i)
#pragma unroll
      for (int nt = 0; nt < 4; ++nt)
#pragma unroll
        for (int r = 0; r < 4; ++r)
          P[(i * 16 + quad * 4 + r) * 72 + nt * 16 + m16] = (bf16)s[i][nt][r];
    __syncthreads();
#pragma unroll
    for (int ks = 0; ks < 2; ++ks) {
      bf16x8 ap[4], bv[4];
#pragma unroll
      for (int i = 0; i < 4; ++i)
        ap[i] = *(const bf16x8*)&P[(i * 16 + m16) * 72 + ks * 32 + quad * 8];
#pragma unroll
      for (int j = 0; j < 4; ++j)
        bv[j] = *(const bf16x8*)&Vt[(j * 16 + m16) * 72 + ks * 32 + quad * 8];
#pragma unroll
      for (int i = 0; i < 4; ++i)
#pragma unroll
        for (int j = 0; j < 4; ++j) o[i][j] = MFMA_BF16(ap[i], bv[j], o[i][j]);
    }
  }

  const size_t obase = ((size_t)bh * NSPLIT + sp) * 4096;
#pragma unroll
  for (int i = 0; i < 4; ++i)
#pragma unroll
    for (int j = 0; j < 4; ++j)
#pragma unroll
      for (int r = 0; r < 4; ++r)
        Opart[obase + (size_t)(i * 16 + quad * 4 + r) * 64 + j * 16 + m16] =
            o[i][j][r];
  if (m16 == 0) {
    const size_t mbase = ((size_t)bh * NSPLIT + sp) * 64;
#pragma unroll
    for (int i = 0; i < 4; ++i)
#pragma unroll
      for (int r = 0; r < 4; ++r) {
        Mpart[mbase + i * 16 + quad * 4 + r] = m_run[i][r];
        Lpart[mbase + i * 16 + quad * 4 + r] = l_run[i][r];
      }
  }
}

__global__ __launch_bounds__(64) void static_merge(
    const float* __restrict__ Opart, const float* __restrict__ Mpart,
    const float* __restrict__ Lpart, bf16* __restrict__ Sout) {
  const int bh = blockIdx.x;
  const int b = bh >> 4, h = bh & 15;
  const int lane = threadIdx.x;
  for (int r = 0; r < 64; ++r) {
    float M = -1e30f;
    float ms[NSPLIT];
#pragma unroll
    for (int s = 0; s < NSPLIT; ++s) {
      ms[s] = Mpart[((size_t)bh * NSPLIT + s) * 64 + r];
      M = fmaxf(M, ms[s]);
    }
    float L = 0.0f;
    float acc = 0.0f;
#pragma unroll
    for (int s = 0; s < NSPLIT; ++s) {
      const float w = __expf(ms[s] - M);
      L += Lpart[((size_t)bh * NSPLIT + s) * 64 + r] * w;
      acc += w * Opart[(((size_t)bh * NSPLIT + s) * 64 + r) * 64 + lane];
    }
    Sout[((size_t)(b * 64 + r)) * DD + h * 64 + lane] = (bf16)(acc / L);
  }
}

__global__ __launch_bounds__(256) void gather_qs(const bf16* __restrict__ Q,
                                                 bf16* __restrict__ Q2in) {
  const int t = blockIdx.x * 256 + threadIdx.x;  // 65536 total
  const int row = t >> 7;
  const int cc = (t & 127) * 8;
  const int b = row >> 6, i = row & 63;
  *(bf16x8*)&Q2in[(size_t)row * DD + cc] =
      *(const bf16x8*)&Q[((size_t)b * LL + NTT + i) * DD + cc];
}

__global__ __launch_bounds__(256) void scatter_out(const bf16* __restrict__ S,
                                                   void* __restrict__ Out,
                                                   const int* __restrict__ dflag) {
  const int f = *dflag;
  const int t = blockIdx.x * 256 + threadIdx.x;
  const int row = t >> 7;
  const int cc = (t & 127) * 8;
  const int b = row >> 6, i = row & 63;
  storeOut8(Out, ((size_t)b * LL + NTT + i) * DD + cc, &S[(size_t)row * DD + cc],
            f);
}

extern "C" void kernel_launch(void* const* d_in, const int* in_sizes, int n_in,
                              void* d_out, int out_size, void* d_ws,
                              size_t ws_size, hipStream_t stream) {
  // Size-driven input identification (dtype-independent: sizes are element
  // counts). q,k,v = the 34078720s in order; Wq,Wk,Wv,out_w = the 1048576s;
  // bq,bk,bv,out_b = the 1024s; masks 32768/512; in_proj 3145728/3072.
  const void* qkv[3] = {nullptr, nullptr, nullptr};
  const void* W4[4] = {nullptr, nullptr, nullptr, nullptr};
  const void* b4[4] = {nullptr, nullptr, nullptr, nullptr};
  const void *tmask = nullptr, *smask = nullptr, *ipw = nullptr, *ipb = nullptr;
  int nbig = 0, nw = 0, nb_ = 0;
  for (int i = 0; i < n_in; ++i) {
    switch (in_sizes[i]) {
      case 34078720: if (nbig < 3) qkv[nbig++] = d_in[i]; break;
      case 32768: tmask = d_in[i]; break;
      case 512: smask = d_in[i]; break;
      case 1048576: if (nw < 4) W4[nw++] = d_in[i]; break;
      case 1024: if (nb_ < 4) b4[nb_++] = d_in[i]; break;
      case 3145728: ipw = d_in[i]; break;
      case 3072: ipb = d_in[i]; break;
      default: break;
    }
  }

  char* w = (char*)d_ws;
  int* dflag = (int*)w; w += 256;
  const size_t BIG = (size_t)NTOK * DD * 2;  // 68,157,440 B
  bf16* Qb = (bf16*)w;  w += BIG;
  bf16* Kb = (bf16*)w;  w += BIG;
  bf16* Vb = (bf16*)w;  w += BIG;
  bf16* Q2in = (bf16*)w;  w += (size_t)512 * DD * 2;
  bf16* Q2 = (bf16*)w;    w += (size_t)512 * DD * 2;
  bf16* SoutB = (bf16*)w; w += (size_t)512 * DD * 2;
  bf16* SoutF = (bf16*)w; w += (size_t)512 * DD * 2;
  float* Opart = (float*)w; w += (size_t)128 * NSPLIT * 4096 * 4;
  float* Mpart = (float*)w; w += (size_t)128 * NSPLIT * 64 * 4;
  float* Lpart = (float*)w; w += (size_t)128 * NSPLIT * 64 * 4;
  bf16* wW3 = (bf16*)w; w += (size_t)1048576 * 2;  // out_w (live at step 11)
  // Weights dead before static_attn writes Opart (stream-serial): overlay
  // Wq/Wk/Wv/in_proj bf16 copies inside the Opart region (12.6MB <= 27.3MB).
  bf16* wW0 = (bf16*)Opart;
  bf16* wW1 = wW0 + 1048576;
  bf16* wW2 = wW1 + 1048576;
  bf16* wIp = wW2 + 1048576;
  // d_out is dead until temporal_attn: use it as bf16 staging for fp32
  // external qkv (33280*1024 bf16 = exactly out's element count).
  bf16* Xstg = (bf16*)d_out;

  // 0: decide external dtype on-device (deterministic; graph-safe)
  detect_dtype<<<1, 256, 0, stream>>>((const unsigned short*)qkv[0], dflag);
  // 0.x: weights -> bf16 ws (copy if already bf16)
  to_bf16<<<512, 256, 0, stream>>>(W4[0], wW0, 131072, dflag, 0);
  to_bf16<<<512, 256, 0, stream>>>(W4[1], wW1, 131072, dflag, 0);
  to_bf16<<<512, 256, 0, stream>>>(W4[2], wW2, 131072, dflag, 0);
  to_bf16<<<512, 256, 0, stream>>>(W4[3], wW3, 131072, dflag, 0);
  to_bf16<<<1536, 256, 0, stream>>>(ipw, wIp, 393216, dflag, 0);
  // 1-3: QKV projections. If external fp32: stage bf16 copy in d_out scratch
  // (skipped entirely when external already bf16; gemm reads ext directly).
  to_bf16<<<16640, 256, 0, stream>>>(qkv[0], Xstg, 4259840, dflag, 1);
  gemm_bt<<<2080, 256, 0, stream>>>(qkv[0], Xstg, wW0, b4[0], 0, Qb, NTOK, DD,
                                    DD, 8, dflag, 1);
  to_bf16<<<16640, 256, 0, stream>>>(qkv[1], Xstg, 4259840, dflag, 1);
  gemm_bt<<<2080, 256, 0, stream>>>(qkv[1], Xstg, wW1, b4[1], 0, Kb, NTOK, DD,
                                    DD, 8, dflag, 1);
  to_bf16<<<16640, 256, 0, stream>>>(qkv[2], Xstg, 4259840, dflag, 1);
  gemm_bt<<<2080, 256, 0, stream>>>(qkv[2], Xstg, wW2, b4[2], 0, Vb, NTOK, DD,
                                    DD, 8, dflag, 1);
  // 4: gather static Q rows before Qb is reused
  gather_qs<<<256, 256, 0, stream>>>(Qb, Q2in);
  // 5: temporal attention -> Out rows [b*4160, b*4160+4096)
  temporal_attn<<<BB * 64 * HH, 256, 0, stream>>>(Qb, Kb, Vb, tmask, smask,
                                                  d_out, dflag);
  // 6-7: second projections (k2 into Qb, v2 into Kb)
  gemm_bt<<<2080, 256, 0, stream>>>(Kb, Kb, wIp + (size_t)DD * DD, ipb, DD, Qb,
                                    NTOK, DD, DD, 8, dflag, 0);
  gemm_bt<<<2080, 256, 0, stream>>>(Vb, Vb, wIp + (size_t)2 * DD * DD, ipb,
                                    2 * DD, Kb, NTOK, DD, DD, 8, dflag, 0);
  // 8: q2 projection (M=512)
  gemm_bt<<<32, 256, 0, stream>>>(Q2in, Q2in, wIp, ipb, 0, Q2, 512, DD, DD, 8,
                                  dflag, 0);
  // 9-10: static attention (split-K flash) + merge
  static_attn<<<128 * NSPLIT, 64, 0, stream>>>(Q2, Qb, Kb, tmask, smask, Opart,
                                               Mpart, Lpart, dflag);
  static_merge<<<128, 64, 0, stream>>>(Opart, Mpart, Lpart, SoutB);
  // 11-12: output projection + scatter into Out static rows
  gemm_bt<<<32, 256, 0, stream>>>(SoutB, SoutB, wW3, b4[3], 0, SoutF, 512, DD,
                                  DD, 8, dflag, 0);
  scatter_out<<<256, 256, 0, stream>>>(SoutF, d_out, dflag);
}